// Round 7
// baseline (985.460 us; speedup 1.0000x reference)
//
#include <hip/hip_runtime.h>

#define N_NODES 50000
#define N_EDGES 300000
#define G_GRAPHS 1024
#define HID 256
#define NLAYERS 4
// padded CSR: every segment rounded up to a multiple of 4 (worst case +3/node)
// +64 guard slots (zero flag) so prefetch addresses need no clamping
#define PAD_SLOTS (N_EDGES + 3 * N_NODES + 64)
// k_mlp row-tile
#define BMT 224

typedef unsigned short ushort_t;
typedef __attribute__((ext_vector_type(8))) short bf16x8;
typedef __attribute__((ext_vector_type(8))) unsigned short u16x8;
typedef __attribute__((ext_vector_type(4))) float f32x4;

__device__ __forceinline__ float bf2f(ushort_t u) {
  unsigned int x = ((unsigned int)u) << 16;
  return __builtin_bit_cast(float, x);
}
__device__ __forceinline__ ushort_t f2bf(float f) {
  unsigned int x = __builtin_bit_cast(unsigned int, f);
  unsigned int lsb = (x >> 16) & 1u;
  x += 0x7fffu + lsb;
  return (ushort_t)(x >> 16);
}

// h(bf16) = relu(x @ encW + encB)
__global__ __launch_bounds__(256) void k_encoder(const float* __restrict__ x,
    const float* __restrict__ W, const float* __restrict__ b,
    ushort_t* __restrict__ h, int n)
{
  int j = threadIdx.x;
  float wcol[11];
#pragma unroll
  for (int k = 0; k < 11; ++k) wcol[k] = W[k * HID + j];
  float bj = b[j];
  __shared__ float xs[8][11];
  int base = blockIdx.x * 8;
  if (j < 88) {
    int r = j / 11, k = j % 11;
    int row = base + r;
    if (row < n) xs[r][k] = x[row * 11 + k];
  }
  __syncthreads();
#pragma unroll
  for (int r = 0; r < 8; ++r) {
    int row = base + r;
    if (row >= n) break;
    float acc = bj;
#pragma unroll
    for (int k = 0; k < 11; ++k) acc += xs[r][k] * wcol[k];
    h[(size_t)row * HID + j] = f2bf(fmaxf(acc, 0.f));
  }
}

// ---- CSR build (padded) ----
__global__ __launch_bounds__(256) void k_hist(const int* __restrict__ dst,
    int* __restrict__ offs, int E)
{
  int e = blockIdx.x * 256 + threadIdx.x;
  if (e < E) atomicAdd(&offs[dst[e]], 1);
}

// chunk-scan of PADDED counts: exclusive scan of ceil4(cnt) within
// 1024-chunk, padded chunk totals to btot
__global__ __launch_bounds__(1024) void k_scanA(int* __restrict__ offs,
    int* __restrict__ btot, int n)
{
  __shared__ int wsum[16];
  int tid = threadIdx.x, lane = tid & 63, wid = tid >> 6;
  int idx = blockIdx.x * 1024 + tid;
  int cnt = (idx < n) ? offs[idx] : 0;
  int v = (cnt + 3) & ~3;  // padded segment length
  int x = v;
#pragma unroll
  for (int off = 1; off < 64; off <<= 1) {
    int t = __shfl_up(x, off);
    if (lane >= off) x += t;
  }
  if (lane == 63) wsum[wid] = x;
  __syncthreads();
  if (wid == 0 && lane < 16) {
    int w = wsum[lane];
#pragma unroll
    for (int off = 1; off < 16; off <<= 1) {
      int t = __shfl_up(w, off);
      if (lane >= off) w += t;
    }
    wsum[lane] = w;
  }
  __syncthreads();
  int wbase = (wid == 0) ? 0 : wsum[wid - 1];
  if (idx < n) offs[idx] = wbase + x - v;
  if (tid == 0) btot[blockIdx.x] = wsum[15];
}

// add chunk base; writes BOTH offs (mutable cursor for k_fill) and pstart
// (read-only padded starts for k_gather). pstart[n] = grand total.
__global__ __launch_bounds__(1024) void k_scanC(int* __restrict__ offs,
    int* __restrict__ pstart, const int* __restrict__ btot, int n)
{
  __shared__ int sbase;
  if (threadIdx.x == 0) {
    int s = 0;
    for (int i = 0; i < (int)blockIdx.x; ++i) s += btot[i];
    sbase = s;
    if (blockIdx.x == gridDim.x - 1) pstart[n] = s + btot[blockIdx.x];
  }
  __syncthreads();
  int idx = blockIdx.x * 1024 + threadIdx.x;
  if (idx < n) {
    int v = offs[idx] + sbase;
    offs[idx] = v;
    pstart[idx] = v;
  }
}

// fill CSR slots: esrc[p] = src, eab[p] = edge_attr packed to 8 bf16.
// eab[5] = 1.0 valid flag (pad slots stay 0 from the memset -> contribute 0).
__global__ __launch_bounds__(256) void k_fill(const int* __restrict__ src,
    const int* __restrict__ dst, int* __restrict__ offs,
    int* __restrict__ esrc, ushort_t* __restrict__ eab,
    const float* __restrict__ ea, int E)
{
  int e = blockIdx.x * 256 + threadIdx.x;
  if (e < E) {
    int d = dst[e];
    int p = atomicAdd(&offs[d], 1);
    esrc[p] = src[e];
    const float* ep = ea + (size_t)e * 5;
    ushort4 lo = make_ushort4(f2bf(ep[0]), f2bf(ep[1]), f2bf(ep[2]), f2bf(ep[3]));
    ushort4 hi = make_ushort4(f2bf(ep[4]), (ushort_t)0x3f80u, 0, 0);
    *(ushort4*)&eab[(size_t)p * 8] = lo;
    *(ushort4*)&eab[(size_t)p * 8 + 4] = hi;
  }
}

// W [256][256] f32 -> Wt [n][k] bf16 (transposed); handles W1 and W2 stacks
__global__ __launch_bounds__(256) void k_prep(const float* __restrict__ W1,
    const float* __restrict__ W2, ushort_t* __restrict__ Wt1,
    ushort_t* __restrict__ Wt2)
{
  __shared__ float ld[16][257];
  int mat = blockIdx.y & (NLAYERS - 1);
  int which = blockIdx.y >> 2;
  const float* Wm = (which ? W2 : W1) + (size_t)mat * HID * HID;
  ushort_t* Wtm = (which ? Wt2 : Wt1) + (size_t)mat * HID * HID;
  int k0 = blockIdx.x * 16;
  int tid = threadIdx.x;
#pragma unroll
  for (int i = 0; i < 16; ++i) ld[i][tid] = Wm[(size_t)(k0 + i) * HID + tid];
  __syncthreads();
#pragma unroll
  for (int v = 0; v < 4; ++v) {
    ushort4 u = make_ushort4(f2bf(ld[v*4+0][tid]), f2bf(ld[v*4+1][tid]),
                             f2bf(ld[v*4+2][tid]), f2bf(ld[v*4+3][tid]));
    *(ushort4*)&Wtm[(size_t)tid * HID + k0 + v * 4] = u;
  }
}

// generic W [K][N] f32 -> Wt [N][K] bf16
__global__ __launch_bounds__(256) void k_prept(const float* __restrict__ W,
    ushort_t* __restrict__ Wt, int K, int N)
{
  int idx = blockIdx.x * 256 + threadIdx.x;
  if (idx >= K * N) return;
  int n = idx / K, k = idx % K;
  Wt[idx] = f2bf(W[(size_t)k * N + n]);
}

// per-edge MLP+accumulate with validity flag (pad slots: flag=0 -> no-op)
__device__ __forceinline__ void edge_step(bf16x8 ev, ushort4 hv,
    const float4& w0, const float4& w1, const float4& w2, const float4& w3,
    const float4& w4, const float4& bi,
    float& ax, float& ay, float& az, float& aw)
{
  float v0 = bf2f((ushort_t)ev[0]), v1 = bf2f((ushort_t)ev[1]),
        v2 = bf2f((ushort_t)ev[2]), v3 = bf2f((ushort_t)ev[3]),
        v4 = bf2f((ushort_t)ev[4]), fl = bf2f((ushort_t)ev[5]);
  float m0 = bi.x, m1 = bi.y, m2 = bi.z, m3 = bi.w;
  m0 = fmaf(v0, w0.x, m0); m1 = fmaf(v0, w0.y, m1);
  m2 = fmaf(v0, w0.z, m2); m3 = fmaf(v0, w0.w, m3);
  m0 = fmaf(v1, w1.x, m0); m1 = fmaf(v1, w1.y, m1);
  m2 = fmaf(v1, w1.z, m2); m3 = fmaf(v1, w1.w, m3);
  m0 = fmaf(v2, w2.x, m0); m1 = fmaf(v2, w2.y, m1);
  m2 = fmaf(v2, w2.z, m2); m3 = fmaf(v2, w2.w, m3);
  m0 = fmaf(v3, w3.x, m0); m1 = fmaf(v3, w3.y, m1);
  m2 = fmaf(v3, w3.z, m2); m3 = fmaf(v3, w3.w, m3);
  m0 = fmaf(v4, w4.x, m0); m1 = fmaf(v4, w4.y, m1);
  m2 = fmaf(v4, w4.z, m2); m3 = fmaf(v4, w4.w, m3);
  m0 += bf2f(hv.x); m1 += bf2f(hv.y); m2 += bf2f(hv.z); m3 += bf2f(hv.w);
  ax = fmaf(fl, fmaxf(m0, 0.f), ax);
  ay = fmaf(fl, fmaxf(m1, 0.f), ay);
  az = fmaf(fl, fmaxf(m2, 0.f), az);
  aw = fmaf(fl, fmaxf(m3, 0.f), aw);
}

// 8-slot ping-pong pipeline, 4 adjacent nodes per wave over one contiguous
// padded-CSR stream. Block 0 zeroes stats for the layer.
__global__ __launch_bounds__(256) void k_gather(const ushort_t* __restrict__ h,
    const int* __restrict__ pstart, const int* __restrict__ esrc,
    const ushort_t* __restrict__ eab, const float* __restrict__ eW,
    const float* __restrict__ eb, ushort_t* __restrict__ zin,
    float* __restrict__ stats, int n)
{
  int tid = threadIdx.x;
  if (blockIdx.x == 0) { stats[tid] = 0.f; stats[HID + tid] = 0.f; }
  int wave = tid >> 6, lane = tid & 63;
  int c4 = lane * 4;
  float4 w0 = *(const float4*)&eW[0 * HID + c4];
  float4 w1 = *(const float4*)&eW[1 * HID + c4];
  float4 w2 = *(const float4*)&eW[2 * HID + c4];
  float4 w3 = *(const float4*)&eW[3 * HID + c4];
  float4 w4 = *(const float4*)&eW[4 * HID + c4];
  float4 bi = *(const float4*)&eb[c4];
  int n0 = (blockIdx.x * 4 + wave) * 4;
  if (n0 >= n) return;
  int e0 = __builtin_amdgcn_readfirstlane(pstart[n0]);
  int e1 = __builtin_amdgcn_readfirstlane(pstart[n0 + 1]);
  int e2 = __builtin_amdgcn_readfirstlane(pstart[n0 + 2]);
  int e3 = __builtin_amdgcn_readfirstlane(pstart[n0 + 3]);
  int e4 = __builtin_amdgcn_readfirstlane(pstart[n0 + 4]);
  float A[4][4];
#pragma unroll
  for (int j = 0; j < 4; ++j) {
    ushort4 hv = *(const ushort4*)&h[(size_t)(n0 + j) * HID + c4];
    A[j][0] = bf2f(hv.x); A[j][1] = bf2f(hv.y);
    A[j][2] = bf2f(hv.z); A[j][3] = bf2f(hv.w);
  }
  int p = e0, pend = e4;
  if (p < pend) {
    int sA0 = esrc[p],     sA1 = esrc[p + 1], sA2 = esrc[p + 2], sA3 = esrc[p + 3];
    int sB0 = esrc[p + 4], sB1 = esrc[p + 5], sB2 = esrc[p + 6], sB3 = esrc[p + 7];
    bf16x8 eaA0 = *(const bf16x8*)&eab[(size_t)(p + 0) * 8];
    bf16x8 eaA1 = *(const bf16x8*)&eab[(size_t)(p + 1) * 8];
    bf16x8 eaA2 = *(const bf16x8*)&eab[(size_t)(p + 2) * 8];
    bf16x8 eaA3 = *(const bf16x8*)&eab[(size_t)(p + 3) * 8];
    bf16x8 eaB0 = *(const bf16x8*)&eab[(size_t)(p + 4) * 8];
    bf16x8 eaB1 = *(const bf16x8*)&eab[(size_t)(p + 5) * 8];
    bf16x8 eaB2 = *(const bf16x8*)&eab[(size_t)(p + 6) * 8];
    bf16x8 eaB3 = *(const bf16x8*)&eab[(size_t)(p + 7) * 8];
    ushort4 hA0 = *(const ushort4*)&h[(size_t)sA0 * HID + c4];
    ushort4 hA1 = *(const ushort4*)&h[(size_t)sA1 * HID + c4];
    ushort4 hA2 = *(const ushort4*)&h[(size_t)sA2 * HID + c4];
    ushort4 hA3 = *(const ushort4*)&h[(size_t)sA3 * HID + c4];
    ushort4 hB0 = *(const ushort4*)&h[(size_t)sB0 * HID + c4];
    ushort4 hB1 = *(const ushort4*)&h[(size_t)sB1 * HID + c4];
    ushort4 hB2 = *(const ushort4*)&h[(size_t)sB2 * HID + c4];
    ushort4 hB3 = *(const ushort4*)&h[(size_t)sB3 * HID + c4];
    int sC0 = esrc[p + 8],  sC1 = esrc[p + 9],  sC2 = esrc[p + 10], sC3 = esrc[p + 11];
    int sD0 = esrc[p + 12], sD1 = esrc[p + 13], sD2 = esrc[p + 14], sD3 = esrc[p + 15];
    while (true) {
      {
        float c0 = 0.f, c1 = 0.f, c2 = 0.f, c3 = 0.f;
        edge_step(eaA0, hA0, w0, w1, w2, w3, w4, bi, c0, c1, c2, c3);
        edge_step(eaA1, hA1, w0, w1, w2, w3, w4, bi, c0, c1, c2, c3);
        edge_step(eaA2, hA2, w0, w1, w2, w3, w4, bi, c0, c1, c2, c3);
        edge_step(eaA3, hA3, w0, w1, w2, w3, w4, bi, c0, c1, c2, c3);
        if (p < e1)      { A[0][0] += c0; A[0][1] += c1; A[0][2] += c2; A[0][3] += c3; }
        else if (p < e2) { A[1][0] += c0; A[1][1] += c1; A[1][2] += c2; A[1][3] += c3; }
        else if (p < e3) { A[2][0] += c0; A[2][1] += c1; A[2][2] += c2; A[2][3] += c3; }
        else             { A[3][0] += c0; A[3][1] += c1; A[3][2] += c2; A[3][3] += c3; }
      }
      p += 4;
      if (p >= pend) break;
      eaA0 = *(const bf16x8*)&eab[(size_t)(p + 4) * 8];
      eaA1 = *(const bf16x8*)&eab[(size_t)(p + 5) * 8];
      eaA2 = *(const bf16x8*)&eab[(size_t)(p + 6) * 8];
      eaA3 = *(const bf16x8*)&eab[(size_t)(p + 7) * 8];
      hA0 = *(const ushort4*)&h[(size_t)sC0 * HID + c4];
      hA1 = *(const ushort4*)&h[(size_t)sC1 * HID + c4];
      hA2 = *(const ushort4*)&h[(size_t)sC2 * HID + c4];
      hA3 = *(const ushort4*)&h[(size_t)sC3 * HID + c4];
      sC0 = esrc[p + 12]; sC1 = esrc[p + 13]; sC2 = esrc[p + 14]; sC3 = esrc[p + 15];
      {
        float c0 = 0.f, c1 = 0.f, c2 = 0.f, c3 = 0.f;
        edge_step(eaB0, hB0, w0, w1, w2, w3, w4, bi, c0, c1, c2, c3);
        edge_step(eaB1, hB1, w0, w1, w2, w3, w4, bi, c0, c1, c2, c3);
        edge_step(eaB2, hB2, w0, w1, w2, w3, w4, bi, c0, c1, c2, c3);
        edge_step(eaB3, hB3, w0, w1, w2, w3, w4, bi, c0, c1, c2, c3);
        if (p < e1)      { A[0][0] += c0; A[0][1] += c1; A[0][2] += c2; A[0][3] += c3; }
        else if (p < e2) { A[1][0] += c0; A[1][1] += c1; A[1][2] += c2; A[1][3] += c3; }
        else if (p < e3) { A[2][0] += c0; A[2][1] += c1; A[2][2] += c2; A[2][3] += c3; }
        else             { A[3][0] += c0; A[3][1] += c1; A[3][2] += c2; A[3][3] += c3; }
      }
      p += 4;
      if (p >= pend) break;
      eaB0 = *(const bf16x8*)&eab[(size_t)(p + 4) * 8];
      eaB1 = *(const bf16x8*)&eab[(size_t)(p + 5) * 8];
      eaB2 = *(const bf16x8*)&eab[(size_t)(p + 6) * 8];
      eaB3 = *(const bf16x8*)&eab[(size_t)(p + 7) * 8];
      hB0 = *(const ushort4*)&h[(size_t)sD0 * HID + c4];
      hB1 = *(const ushort4*)&h[(size_t)sD1 * HID + c4];
      hB2 = *(const ushort4*)&h[(size_t)sD2 * HID + c4];
      hB3 = *(const ushort4*)&h[(size_t)sD3 * HID + c4];
      sD0 = esrc[p + 12]; sD1 = esrc[p + 13]; sD2 = esrc[p + 14]; sD3 = esrc[p + 15];
    }
  }
#pragma unroll
  for (int j = 0; j < 4; ++j) {
    *(ushort4*)&zin[(size_t)(n0 + j) * HID + c4] =
        make_ushort4(f2bf(A[j][0]), f2bf(A[j][1]), f2bf(A[j][2]), f2bf(A[j][3]));
  }
}

// Fused layer MLP: one 224x256 row-tile per block, both GEMM stages fused.
// Round-25: template<FUSE>. FUSE=1 (layers 0-2) additionally fuses BatchNorm
// + relu + residual via a device-wide arrive-and-spin barrier:
//   grid 224 blocks at 1 block/CU (118KB LDS) on 256 CUs -> all co-resident
//   -> spin barrier is deadlock-free without cooperative launch.
// acc (z2) stays in registers across the barrier; stats re-read through
// unsafeAtomicAdd(ptr, 0) (coherent point -> immune to XCD-L2 staleness).
// Deletes k_bn_apply (77MB round-trip) and the z2 global store per fused
// layer. Replay-safe: bar pre-zeroed per launch; bar>=grid falls through.
template<int FUSE>
__global__ __launch_bounds__(512, 1) void k_mlp(const ushort_t* __restrict__ A,
    const ushort_t* __restrict__ Wt1, const float* __restrict__ b1,
    const ushort_t* __restrict__ Wt2, const float* __restrict__ b2,
    ushort_t* __restrict__ out, float* __restrict__ stats, int M,
    const float* __restrict__ bng, const float* __restrict__ bnb,
    ushort_t* __restrict__ hbuf, int* __restrict__ bar)
{
  __shared__ alignas(16) ushort_t T[BMT][264];  // A-tile, then z1 (118 KB)
  int tid = threadIdx.x;
  int wave = tid >> 6, lane = tid & 63;
  int m = lane & 15, quad = lane >> 4;
  int col0 = wave * 32;
  int row0 = blockIdx.x * BMT;

  // ---- stage A-tile -> LDS (coalesced b128; rows >= M clamp to M-1) ----
#pragma unroll
  for (int i = 0; i < 14; ++i) {
    int flat = i * 512 + tid;
    int row = flat >> 5, kc = flat & 31;
    int gr = row0 + row; if (gr > M - 1) gr = M - 1;
    u16x8 v = *(const u16x8*)(A + (size_t)gr * HID + kc * 8);
    *(u16x8*)&T[row][kc * 8] = v;
  }
  bf16x8 w1f[2][8];
#pragma unroll
  for (int nt = 0; nt < 2; ++nt)
#pragma unroll
    for (int kt = 0; kt < 8; ++kt)
      w1f[nt][kt] = *(const bf16x8*)(
          Wt1 + (size_t)(col0 + nt * 16 + m) * HID + kt * 32 + quad * 8);
  float bv1[2] = {b1[col0 + m], b1[col0 + 16 + m]};
  float bv2[2] = {b2[col0 + m], b2[col0 + 16 + m]};
  __syncthreads();

  // ---- stage 1: z1 = relu(A@W1+b1) ----
  f32x4 acc[14][2];
#pragma unroll
  for (int mt = 0; mt < 14; ++mt) {
    acc[mt][0] = (f32x4){0.f, 0.f, 0.f, 0.f};
    acc[mt][1] = (f32x4){0.f, 0.f, 0.f, 0.f};
    bf16x8 af[8];
#pragma unroll
    for (int kt = 0; kt < 8; ++kt)
      af[kt] = *(const bf16x8*)&T[mt * 16 + m][kt * 32 + quad * 8];
#pragma unroll
    for (int kt = 0; kt < 8; ++kt) {
      acc[mt][0] = __builtin_amdgcn_mfma_f32_16x16x32_bf16(af[kt], w1f[0][kt], acc[mt][0], 0, 0, 0);
      acc[mt][1] = __builtin_amdgcn_mfma_f32_16x16x32_bf16(af[kt], w1f[1][kt], acc[mt][1], 0, 0, 0);
    }
  }
  __syncthreads();

  // ---- z1 overwrites A-LDS ----
#pragma unroll
  for (int mt = 0; mt < 14; ++mt)
#pragma unroll
    for (int nt = 0; nt < 2; ++nt)
#pragma unroll
      for (int reg = 0; reg < 4; ++reg)
        T[mt * 16 + quad * 4 + reg][col0 + nt * 16 + m] =
            f2bf(fmaxf(acc[mt][nt][reg] + bv1[nt], 0.f));
  bf16x8 w2f[2][8];
#pragma unroll
  for (int nt = 0; nt < 2; ++nt)
#pragma unroll
    for (int kt = 0; kt < 8; ++kt)
      w2f[nt][kt] = *(const bf16x8*)(
          Wt2 + (size_t)(col0 + nt * 16 + m) * HID + kt * 32 + quad * 8);
  __syncthreads();

  // ---- stage 2: z2 = z1@W2+b2 ----
#pragma unroll
  for (int mt = 0; mt < 14; ++mt) {
    acc[mt][0] = (f32x4){0.f, 0.f, 0.f, 0.f};
    acc[mt][1] = (f32x4){0.f, 0.f, 0.f, 0.f};
    bf16x8 af[8];
#pragma unroll
    for (int kt = 0; kt < 8; ++kt)
      af[kt] = *(const bf16x8*)&T[mt * 16 + m][kt * 32 + quad * 8];
#pragma unroll
    for (int kt = 0; kt < 8; ++kt) {
      acc[mt][0] = __builtin_amdgcn_mfma_f32_16x16x32_bf16(af[kt], w2f[0][kt], acc[mt][0], 0, 0, 0);
      acc[mt][1] = __builtin_amdgcn_mfma_f32_16x16x32_bf16(af[kt], w2f[1][kt], acc[mt][1], 0, 0, 0);
    }
  }

  // ---- stats (z2 pre-BN), and for FUSE=0 the z2 store ----
  float csum[2] = {0.f, 0.f}, csq[2] = {0.f, 0.f};
#pragma unroll
  for (int mt = 0; mt < 14; ++mt) {
    if (row0 + mt * 16 < M) {
#pragma unroll
      for (int nt = 0; nt < 2; ++nt) {
#pragma unroll
        for (int reg = 0; reg < 4; ++reg) {
          float o = acc[mt][nt][reg] + bv2[nt];
          if (!FUSE)
            out[(size_t)(row0 + mt * 16 + quad * 4 + reg) * HID + col0 + nt * 16 + m] = f2bf(o);
          csum[nt] += o; csq[nt] = fmaf(o, o, csq[nt]);
        }
      }
    }
  }
#pragma unroll
  for (int nt = 0; nt < 2; ++nt) {
    float s = csum[nt], q = csq[nt];
    s += __shfl_xor(s, 16); s += __shfl_xor(s, 32);
    q += __shfl_xor(q, 16); q += __shfl_xor(q, 32);
    if (quad == 0) {
      unsafeAtomicAdd(&stats[col0 + nt * 16 + m], s);
      unsafeAtomicAdd(&stats[HID + col0 + nt * 16 + m], q);
    }
  }

  if (FUSE) {
    // ---- device-wide arrive-and-spin barrier (all 224 blocks co-resident) ----
    __threadfence();
    __syncthreads();           // all this block's stats atomics complete
    if (tid == 0) {
      atomicAdd(bar, 1);
      while (atomicAdd(bar, 0) < (int)gridDim.x) __builtin_amdgcn_s_sleep(1);
    }
    __syncthreads();
    // ---- BN + relu + residual, write h directly ----
    const float inv_n = 1.f / (float)N_NODES;
    float sc[2], sh[2];
#pragma unroll
    for (int nt = 0; nt < 2; ++nt) {
      int c = col0 + nt * 16 + m;
      float S = unsafeAtomicAdd(&stats[c], 0.f);        // coherent read
      float Q = unsafeAtomicAdd(&stats[HID + c], 0.f);
      float mu = S * inv_n;
      float var = Q * inv_n - mu * mu;
      float rs = rsqrtf(var + 1e-5f);
      sc[nt] = bng[c] * rs;
      sh[nt] = bnb[c] - mu * sc[nt];
    }
#pragma unroll
    for (int mt = 0; mt < 14; ++mt) {
      if (row0 + mt * 16 < M) {
#pragma unroll
        for (int nt = 0; nt < 2; ++nt) {
          int c = col0 + nt * 16 + m;
#pragma unroll
          for (int reg = 0; reg < 4; ++reg) {
            size_t idx = (size_t)(row0 + mt * 16 + quad * 4 + reg) * HID + c;
            float o = acc[mt][nt][reg] + bv2[nt];
            float hv = bf2f(hbuf[idx]);
            hbuf[idx] = f2bf(fmaxf(fmaf(o, sc[nt], sh[nt]), 0.f) + hv);
          }
        }
      }
    }
  }
}

__device__ __forceinline__ int lbound(const int* __restrict__ b, int n, int key) {
  int lo = 0, hi = n;
  while (lo < hi) {
    int mid = (lo + hi) >> 1;
    if (b[mid] < key) lo = mid + 1; else hi = mid;
  }
  return lo;
}

// fused last-layer BN + pool: h_new = relu(z2*sc+sh) + h_old computed on
// the fly. gf[g] = [mean | sum | max] as bf16.
__global__ __launch_bounds__(256) void k_pool_bn(const ushort_t* __restrict__ z,
    const float* __restrict__ stats, const float* __restrict__ g_,
    const float* __restrict__ b_, const ushort_t* __restrict__ h,
    const int* __restrict__ batch, ushort_t* __restrict__ gf)
{
  int g = blockIdx.x, j = threadIdx.x;
  const float inv_n = 1.f / (float)N_NODES;
  float mu = stats[j] * inv_n;
  float var = stats[HID + j] * inv_n - mu * mu;
  float rs = rsqrtf(var + 1e-5f);
  float sc = g_[j] * rs;
  float sh = b_[j] - mu * sc;
  int lo = lbound(batch, N_NODES, g);
  int hi = lbound(batch, N_NODES, g + 1);
  float s = 0.f, mx = 0.f;  // h >= 0 by construction
  for (int i = lo; i < hi; ++i) {
    float zv = bf2f(z[(size_t)i * HID + j]);
    float hv = bf2f(h[(size_t)i * HID + j]);
    float v = fmaxf(fmaf(zv, sc, sh), 0.f) + hv;
    s += v; mx = fmaxf(mx, v);
  }
  float cntv = fmaxf((float)(hi - lo), 1.f);
  size_t base = (size_t)g * 768;
  gf[base + j] = f2bf(s / cntv);
  gf[base + 256 + j] = f2bf(s);
  gf[base + 512 + j] = f2bf(mx);
}

// small B-in-registers MFMA GEMM for the head: out[M,N] = A[M,K] @ Bt^T + bias
template<int KT, int DO_RELU>
__global__ __launch_bounds__(256, 1) void k_head_gemm(const ushort_t* __restrict__ A,
    const ushort_t* __restrict__ Bt, const float* __restrict__ bias,
    ushort_t* __restrict__ out, int M, int N)
{
  const int K = KT * 32;
  int tid = threadIdx.x;
  int wave = tid >> 6, lane = tid & 63;
  int m = lane & 15, quad = lane >> 4;
  int col = (blockIdx.y * 4 + wave) * 16 + m;
  bf16x8 bfrag[KT];
#pragma unroll
  for (int kt = 0; kt < KT; ++kt)
    bfrag[kt] = *(const bf16x8*)(Bt + (size_t)col * K + kt * 32 + quad * 8);
  float bv = bias[col];
  int ntiles = M >> 4;
  for (int t = blockIdx.x; t < ntiles; t += gridDim.x) {
    const ushort_t* Ap = A + (size_t)(t * 16 + m) * K + quad * 8;
    bf16x8 af[KT];
#pragma unroll
    for (int kt = 0; kt < KT; ++kt) af[kt] = *(const bf16x8*)(Ap + kt * 32);
    f32x4 acc = (f32x4){0.f, 0.f, 0.f, 0.f};
#pragma unroll
    for (int kt = 0; kt < KT; ++kt)
      acc = __builtin_amdgcn_mfma_f32_16x16x32_bf16(af[kt], bfrag[kt], acc, 0, 0, 0);
    int rb = t * 16 + quad * 4;
#pragma unroll
    for (int reg = 0; reg < 4; ++reg) {
      float o = acc[reg] + bv;
      if (DO_RELU) o = fmaxf(o, 0.f);
      out[(size_t)(rb + reg) * N + col] = f2bf(o);
    }
  }
}

// out[g] = dot(g2[g], W3) + b3; one wave per graph
__global__ __launch_bounds__(256) void k_head_out(const ushort_t* __restrict__ g2,
    const float* __restrict__ W3, const float* __restrict__ b3,
    float* __restrict__ out)
{
  int wave = threadIdx.x >> 6, lane = threadIdx.x & 63;
  int g = blockIdx.x * 4 + wave;
  ushort2 v = *(const ushort2*)&g2[(size_t)g * 128 + lane * 2];
  float p = bf2f(v.x) * W3[lane * 2] + bf2f(v.y) * W3[lane * 2 + 1];
#pragma unroll
  for (int off = 32; off > 0; off >>= 1) p += __shfl_down(p, off);
  if (lane == 0) out[g] = p + b3[0];
}

extern "C" void kernel_launch(void* const* d_in, const int* in_sizes, int n_in,
                              void* d_out, int out_size, void* d_ws, size_t ws_size,
                              hipStream_t stream)
{
  const float* x     = (const float*)d_in[0];
  const int*   ei    = (const int*)d_in[1];
  const float* ea    = (const float*)d_in[2];
  const int*   batch = (const int*)d_in[3];
  const float* encW  = (const float*)d_in[4];
  const float* encB  = (const float*)d_in[5];
  const float* edgeW = (const float*)d_in[6];
  const float* edgeB = (const float*)d_in[7];
  const float* W1    = (const float*)d_in[8];
  const float* b1    = (const float*)d_in[9];
  const float* W2    = (const float*)d_in[10];
  const float* b2    = (const float*)d_in[11];
  const float* bng   = (const float*)d_in[12];
  const float* bnb   = (const float*)d_in[13];
  const float* hW1   = (const float*)d_in[14];
  const float* hb1   = (const float*)d_in[15];
  const float* hW2   = (const float*)d_in[16];
  const float* hb2   = (const float*)d_in[17];
  const float* hW3   = (const float*)d_in[18];
  const float* hb3   = (const float*)d_in[19];
  float* out = (float*)d_out;

  const size_t NH = (size_t)N_NODES * HID;
  char* base = (char*)d_ws;
  auto alloc = [&](size_t bytes) -> char* {
    char* p = base; base += (bytes + 63) & ~(size_t)63; return p;
  };
  float*    stats = (float*)alloc(512 * 4);
  int*      bar   = (int*)alloc(16 * 4);
  int*      offs  = (int*)alloc(50001 * 4);
  int*      pstart= (int*)alloc(50001 * 4);
  int*      btot  = (int*)alloc(64 * 4);
  int*      esrc  = (int*)alloc((size_t)PAD_SLOTS * 4);
  ushort_t* eab   = (ushort_t*)alloc((size_t)PAD_SLOTS * 8 * 2);
  ushort_t* Wt1   = (ushort_t*)alloc((size_t)NLAYERS * HID * HID * 2);
  ushort_t* Wt2   = (ushort_t*)alloc((size_t)NLAYERS * HID * HID * 2);
  ushort_t* hW1t  = (ushort_t*)alloc((size_t)768 * 256 * 2);
  ushort_t* hW2t  = (ushort_t*)alloc((size_t)256 * 128 * 2);
  ushort_t* gf    = (ushort_t*)alloc((size_t)G_GRAPHS * 768 * 2);
  ushort_t* g1    = (ushort_t*)alloc((size_t)G_GRAPHS * 256 * 2);
  ushort_t* g2    = (ushort_t*)alloc((size_t)G_GRAPHS * 128 * 2);
  ushort_t* zin   = (ushort_t*)alloc(NH * 2);  // gather out / last-layer z2
  ushort_t* h     = (ushort_t*)alloc(NH * 2);
  // total ~88 MB

  const int* src = ei;
  const int* dst = ei + N_EDGES;

  // setup: padded CSR build + weight prep (once per call)
  hipMemsetAsync(bar, 0, 16 * sizeof(int), stream);
  hipMemsetAsync(offs, 0, 50001 * sizeof(int), stream);
  // esrc and eab are adjacent allocations: one combined clear
  hipMemsetAsync(esrc, 0, (size_t)((char*)(eab + (size_t)PAD_SLOTS * 8) - (char*)esrc), stream);
  k_hist<<<(N_EDGES + 255) / 256, 256, 0, stream>>>(dst, offs, N_EDGES);
  const int NSB = (N_NODES + 1023) / 1024;  // 49
  k_scanA<<<NSB, 1024, 0, stream>>>(offs, btot, N_NODES);
  k_scanC<<<NSB, 1024, 0, stream>>>(offs, pstart, btot, N_NODES);
  k_fill<<<(N_EDGES + 255) / 256, 256, 0, stream>>>(src, dst, offs, esrc, eab, ea, N_EDGES);
  k_prep<<<dim3(16, 2 * NLAYERS), 256, 0, stream>>>(W1, W2, Wt1, Wt2);
  k_prept<<<(768 * 256 + 255) / 256, 256, 0, stream>>>(hW1, hW1t, 768, 256);
  k_prept<<<(256 * 128 + 255) / 256, 256, 0, stream>>>(hW2, hW2t, 256, 128);

  k_encoder<<<(N_NODES + 7) / 8, 256, 0, stream>>>(x, encW, encB, h, N_NODES);

  const int NB_MLP = (N_NODES + BMT - 1) / BMT;  // 224 blocks, 1 tile each

  for (int l = 0; l < NLAYERS; ++l) {
    k_gather<<<(N_NODES + 15) / 16, 256, 0, stream>>>(
        h, pstart, esrc, eab, edgeW + (size_t)l * 5 * HID, edgeB + (size_t)l * HID,
        zin, stats, N_NODES);
    if (l < NLAYERS - 1) {
      k_mlp<1><<<NB_MLP, 512, 0, stream>>>(
          zin, Wt1 + (size_t)l * HID * HID, b1 + (size_t)l * HID,
          Wt2 + (size_t)l * HID * HID, b2 + (size_t)l * HID, nullptr, stats,
          N_NODES, bng + (size_t)l * HID, bnb + (size_t)l * HID, h, bar + l);
    } else {
      k_mlp<0><<<NB_MLP, 512, 0, stream>>>(
          zin, Wt1 + (size_t)l * HID * HID, b1 + (size_t)l * HID,
          Wt2 + (size_t)l * HID * HID, b2 + (size_t)l * HID, zin, stats,
          N_NODES, nullptr, nullptr, nullptr, nullptr);
    }
  }

  // last layer: BN fused into pool (h only read, never re-written)
  k_pool_bn<<<G_GRAPHS, 256, 0, stream>>>(
      zin, stats, bng + (size_t)(NLAYERS - 1) * HID,
      bnb + (size_t)(NLAYERS - 1) * HID, h, batch, gf);
  k_head_gemm<24, 1><<<dim3(16, 4), 256, 0, stream>>>(gf, hW1t, hb1, g1, G_GRAPHS, 256);
  k_head_gemm<8, 1><<<dim3(16, 2), 256, 0, stream>>>(g1, hW2t, hb2, g2, G_GRAPHS, 128);
  k_head_out<<<G_GRAPHS / 4, 256, 0, stream>>>(g2, hW3, hb3, out);
}

// Round 8
// 520.725 us; speedup vs baseline: 1.8925x; 1.8925x over previous
//
#include <hip/hip_runtime.h>

#define N_NODES 50000
#define N_EDGES 300000
#define G_GRAPHS 1024
#define HID 256
#define NLAYERS 4
// padded CSR: every segment rounded up to a multiple of 4 (worst case +3/node)
// +64 guard slots (zero flag) so prefetch addresses need no clamping
#define PAD_SLOTS (N_EDGES + 3 * N_NODES + 64)
// k_mlp row-tile
#define BMT 224

typedef unsigned short ushort_t;
typedef __attribute__((ext_vector_type(8))) short bf16x8;
typedef __attribute__((ext_vector_type(8))) unsigned short u16x8;
typedef __attribute__((ext_vector_type(4))) float f32x4;

__device__ __forceinline__ float bf2f(ushort_t u) {
  unsigned int x = ((unsigned int)u) << 16;
  return __builtin_bit_cast(float, x);
}
__device__ __forceinline__ ushort_t f2bf(float f) {
  unsigned int x = __builtin_bit_cast(unsigned int, f);
  unsigned int lsb = (x >> 16) & 1u;
  x += 0x7fffu + lsb;
  return (ushort_t)(x >> 16);
}

// h(bf16) = relu(x @ encW + encB)
__global__ __launch_bounds__(256) void k_encoder(const float* __restrict__ x,
    const float* __restrict__ W, const float* __restrict__ b,
    ushort_t* __restrict__ h, int n)
{
  int j = threadIdx.x;
  float wcol[11];
#pragma unroll
  for (int k = 0; k < 11; ++k) wcol[k] = W[k * HID + j];
  float bj = b[j];
  __shared__ float xs[8][11];
  int base = blockIdx.x * 8;
  if (j < 88) {
    int r = j / 11, k = j % 11;
    int row = base + r;
    if (row < n) xs[r][k] = x[row * 11 + k];
  }
  __syncthreads();
#pragma unroll
  for (int r = 0; r < 8; ++r) {
    int row = base + r;
    if (row >= n) break;
    float acc = bj;
#pragma unroll
    for (int k = 0; k < 11; ++k) acc += xs[r][k] * wcol[k];
    h[(size_t)row * HID + j] = f2bf(fmaxf(acc, 0.f));
  }
}

// ---- CSR build (padded) ----
__global__ __launch_bounds__(256) void k_hist(const int* __restrict__ dst,
    int* __restrict__ offs, int E)
{
  int e = blockIdx.x * 256 + threadIdx.x;
  if (e < E) atomicAdd(&offs[dst[e]], 1);
}

// chunk-scan of PADDED counts: exclusive scan of ceil4(cnt) within
// 1024-chunk, padded chunk totals to btot
__global__ __launch_bounds__(1024) void k_scanA(int* __restrict__ offs,
    int* __restrict__ btot, int n)
{
  __shared__ int wsum[16];
  int tid = threadIdx.x, lane = tid & 63, wid = tid >> 6;
  int idx = blockIdx.x * 1024 + tid;
  int cnt = (idx < n) ? offs[idx] : 0;
  int v = (cnt + 3) & ~3;  // padded segment length
  int x = v;
#pragma unroll
  for (int off = 1; off < 64; off <<= 1) {
    int t = __shfl_up(x, off);
    if (lane >= off) x += t;
  }
  if (lane == 63) wsum[wid] = x;
  __syncthreads();
  if (wid == 0 && lane < 16) {
    int w = wsum[lane];
#pragma unroll
    for (int off = 1; off < 16; off <<= 1) {
      int t = __shfl_up(w, off);
      if (lane >= off) w += t;
    }
    wsum[lane] = w;
  }
  __syncthreads();
  int wbase = (wid == 0) ? 0 : wsum[wid - 1];
  if (idx < n) offs[idx] = wbase + x - v;
  if (tid == 0) btot[blockIdx.x] = wsum[15];
}

// add chunk base; writes BOTH offs (mutable cursor for k_fill) and pstart
// (read-only padded starts for k_gather). pstart[n] = grand total.
__global__ __launch_bounds__(1024) void k_scanC(int* __restrict__ offs,
    int* __restrict__ pstart, const int* __restrict__ btot, int n)
{
  __shared__ int sbase;
  if (threadIdx.x == 0) {
    int s = 0;
    for (int i = 0; i < (int)blockIdx.x; ++i) s += btot[i];
    sbase = s;
    if (blockIdx.x == gridDim.x - 1) pstart[n] = s + btot[blockIdx.x];
  }
  __syncthreads();
  int idx = blockIdx.x * 1024 + threadIdx.x;
  if (idx < n) {
    int v = offs[idx] + sbase;
    offs[idx] = v;
    pstart[idx] = v;
  }
}

// fill CSR slots: esrc[p] = src, eab[p] = edge_attr packed to 8 bf16.
// eab[5] = 1.0 valid flag (pad slots stay 0 from the memset -> contribute 0).
__global__ __launch_bounds__(256) void k_fill(const int* __restrict__ src,
    const int* __restrict__ dst, int* __restrict__ offs,
    int* __restrict__ esrc, ushort_t* __restrict__ eab,
    const float* __restrict__ ea, int E)
{
  int e = blockIdx.x * 256 + threadIdx.x;
  if (e < E) {
    int d = dst[e];
    int p = atomicAdd(&offs[d], 1);
    esrc[p] = src[e];
    const float* ep = ea + (size_t)e * 5;
    ushort4 lo = make_ushort4(f2bf(ep[0]), f2bf(ep[1]), f2bf(ep[2]), f2bf(ep[3]));
    ushort4 hi = make_ushort4(f2bf(ep[4]), (ushort_t)0x3f80u, 0, 0);
    *(ushort4*)&eab[(size_t)p * 8] = lo;
    *(ushort4*)&eab[(size_t)p * 8 + 4] = hi;
  }
}

// W [256][256] f32 -> Wt [n][k] bf16 (transposed); handles W1 and W2 stacks
__global__ __launch_bounds__(256) void k_prep(const float* __restrict__ W1,
    const float* __restrict__ W2, ushort_t* __restrict__ Wt1,
    ushort_t* __restrict__ Wt2)
{
  __shared__ float ld[16][257];
  int mat = blockIdx.y & (NLAYERS - 1);
  int which = blockIdx.y >> 2;
  const float* Wm = (which ? W2 : W1) + (size_t)mat * HID * HID;
  ushort_t* Wtm = (which ? Wt2 : Wt1) + (size_t)mat * HID * HID;
  int k0 = blockIdx.x * 16;
  int tid = threadIdx.x;
#pragma unroll
  for (int i = 0; i < 16; ++i) ld[i][tid] = Wm[(size_t)(k0 + i) * HID + tid];
  __syncthreads();
#pragma unroll
  for (int v = 0; v < 4; ++v) {
    ushort4 u = make_ushort4(f2bf(ld[v*4+0][tid]), f2bf(ld[v*4+1][tid]),
                             f2bf(ld[v*4+2][tid]), f2bf(ld[v*4+3][tid]));
    *(ushort4*)&Wtm[(size_t)tid * HID + k0 + v * 4] = u;
  }
}

// generic W [K][N] f32 -> Wt [N][K] bf16
__global__ __launch_bounds__(256) void k_prept(const float* __restrict__ W,
    ushort_t* __restrict__ Wt, int K, int N)
{
  int idx = blockIdx.x * 256 + threadIdx.x;
  if (idx >= K * N) return;
  int n = idx / K, k = idx % K;
  Wt[idx] = f2bf(W[(size_t)k * N + n]);
}

// per-edge MLP+accumulate with validity flag (pad slots: flag=0 -> no-op)
__device__ __forceinline__ void edge_step(bf16x8 ev, ushort4 hv,
    const float4& w0, const float4& w1, const float4& w2, const float4& w3,
    const float4& w4, const float4& bi,
    float& ax, float& ay, float& az, float& aw)
{
  float v0 = bf2f((ushort_t)ev[0]), v1 = bf2f((ushort_t)ev[1]),
        v2 = bf2f((ushort_t)ev[2]), v3 = bf2f((ushort_t)ev[3]),
        v4 = bf2f((ushort_t)ev[4]), fl = bf2f((ushort_t)ev[5]);
  float m0 = bi.x, m1 = bi.y, m2 = bi.z, m3 = bi.w;
  m0 = fmaf(v0, w0.x, m0); m1 = fmaf(v0, w0.y, m1);
  m2 = fmaf(v0, w0.z, m2); m3 = fmaf(v0, w0.w, m3);
  m0 = fmaf(v1, w1.x, m0); m1 = fmaf(v1, w1.y, m1);
  m2 = fmaf(v1, w1.z, m2); m3 = fmaf(v1, w1.w, m3);
  m0 = fmaf(v2, w2.x, m0); m1 = fmaf(v2, w2.y, m1);
  m2 = fmaf(v2, w2.z, m2); m3 = fmaf(v2, w2.w, m3);
  m0 = fmaf(v3, w3.x, m0); m1 = fmaf(v3, w3.y, m1);
  m2 = fmaf(v3, w3.z, m2); m3 = fmaf(v3, w3.w, m3);
  m0 = fmaf(v4, w4.x, m0); m1 = fmaf(v4, w4.y, m1);
  m2 = fmaf(v4, w4.z, m2); m3 = fmaf(v4, w4.w, m3);
  m0 += bf2f(hv.x); m1 += bf2f(hv.y); m2 += bf2f(hv.z); m3 += bf2f(hv.w);
  ax = fmaf(fl, fmaxf(m0, 0.f), ax);
  ay = fmaf(fl, fmaxf(m1, 0.f), ay);
  az = fmaf(fl, fmaxf(m2, 0.f), az);
  aw = fmaf(fl, fmaxf(m3, 0.f), aw);
}

// 4 adjacent nodes per wave over one contiguous padded-CSR stream.
// Two-level software pipeline: esrc 2 chunks ahead, eab+h[src] 1 chunk ahead.
// (round-4 structure — best measured; ping-pong variant was neutral/worse)
__global__ __launch_bounds__(256) void k_gather(const ushort_t* __restrict__ h,
    const int* __restrict__ pstart, const int* __restrict__ esrc,
    const ushort_t* __restrict__ eab, const float* __restrict__ eW,
    const float* __restrict__ eb, ushort_t* __restrict__ zin,
    float* __restrict__ stats, int n)
{
  int tid = threadIdx.x;
  if (blockIdx.x == 0) { stats[tid] = 0.f; stats[HID + tid] = 0.f; }
  int wave = tid >> 6, lane = tid & 63;
  int c4 = lane * 4;
  float4 w0 = *(const float4*)&eW[0 * HID + c4];
  float4 w1 = *(const float4*)&eW[1 * HID + c4];
  float4 w2 = *(const float4*)&eW[2 * HID + c4];
  float4 w3 = *(const float4*)&eW[3 * HID + c4];
  float4 w4 = *(const float4*)&eW[4 * HID + c4];
  float4 bi = *(const float4*)&eb[c4];
  int n0 = (blockIdx.x * 4 + wave) * 4;
  if (n0 >= n) return;
  // padded segment boundaries (wave-uniform -> scalar regs)
  int e0 = __builtin_amdgcn_readfirstlane(pstart[n0]);
  int e1 = __builtin_amdgcn_readfirstlane(pstart[n0 + 1]);
  int e2 = __builtin_amdgcn_readfirstlane(pstart[n0 + 2]);
  int e3 = __builtin_amdgcn_readfirstlane(pstart[n0 + 3]);
  int e4 = __builtin_amdgcn_readfirstlane(pstart[n0 + 4]);
  float A[4][4];
#pragma unroll
  for (int j = 0; j < 4; ++j) {
    ushort4 hv = *(const ushort4*)&h[(size_t)(n0 + j) * HID + c4];
    A[j][0] = bf2f(hv.x); A[j][1] = bf2f(hv.y);
    A[j][2] = bf2f(hv.z); A[j][3] = bf2f(hv.w);
  }
  int p = e0, pend = e4;
  bf16x8 ec0, ec1, ec2, ec3;
  ushort4 hc0, hc1, hc2, hc3;
  int sn0, sn1, sn2, sn3;
  if (p < pend) {
    int sc0 = esrc[p], sc1 = esrc[p + 1], sc2 = esrc[p + 2], sc3 = esrc[p + 3];
    ec0 = *(const bf16x8*)&eab[(size_t)(p + 0) * 8];
    ec1 = *(const bf16x8*)&eab[(size_t)(p + 1) * 8];
    ec2 = *(const bf16x8*)&eab[(size_t)(p + 2) * 8];
    ec3 = *(const bf16x8*)&eab[(size_t)(p + 3) * 8];
    hc0 = *(const ushort4*)&h[(size_t)sc0 * HID + c4];
    hc1 = *(const ushort4*)&h[(size_t)sc1 * HID + c4];
    hc2 = *(const ushort4*)&h[(size_t)sc2 * HID + c4];
    hc3 = *(const ushort4*)&h[(size_t)sc3 * HID + c4];
    int pn = (p + 4 < pend) ? p + 4 : p;
    sn0 = esrc[pn]; sn1 = esrc[pn + 1]; sn2 = esrc[pn + 2]; sn3 = esrc[pn + 3];
  }
  for (; p < pend; p += 4) {
    int pn = (p + 4 < pend) ? p + 4 : p;
    int pnn = (p + 8 < pend) ? p + 8 : p;
    bf16x8 en0 = *(const bf16x8*)&eab[(size_t)(pn + 0) * 8];
    bf16x8 en1 = *(const bf16x8*)&eab[(size_t)(pn + 1) * 8];
    bf16x8 en2 = *(const bf16x8*)&eab[(size_t)(pn + 2) * 8];
    bf16x8 en3 = *(const bf16x8*)&eab[(size_t)(pn + 3) * 8];
    ushort4 hn0 = *(const ushort4*)&h[(size_t)sn0 * HID + c4];
    ushort4 hn1 = *(const ushort4*)&h[(size_t)sn1 * HID + c4];
    ushort4 hn2 = *(const ushort4*)&h[(size_t)sn2 * HID + c4];
    ushort4 hn3 = *(const ushort4*)&h[(size_t)sn3 * HID + c4];
    int sm0 = esrc[pnn], sm1 = esrc[pnn + 1], sm2 = esrc[pnn + 2], sm3 = esrc[pnn + 3];
    float c0 = 0.f, c1 = 0.f, c2 = 0.f, c3 = 0.f;
    edge_step(ec0, hc0, w0, w1, w2, w3, w4, bi, c0, c1, c2, c3);
    edge_step(ec1, hc1, w0, w1, w2, w3, w4, bi, c0, c1, c2, c3);
    edge_step(ec2, hc2, w0, w1, w2, w3, w4, bi, c0, c1, c2, c3);
    edge_step(ec3, hc3, w0, w1, w2, w3, w4, bi, c0, c1, c2, c3);
    if (p < e1)      { A[0][0] += c0; A[0][1] += c1; A[0][2] += c2; A[0][3] += c3; }
    else if (p < e2) { A[1][0] += c0; A[1][1] += c1; A[1][2] += c2; A[1][3] += c3; }
    else if (p < e3) { A[2][0] += c0; A[2][1] += c1; A[2][2] += c2; A[2][3] += c3; }
    else             { A[3][0] += c0; A[3][1] += c1; A[3][2] += c2; A[3][3] += c3; }
    ec0 = en0; ec1 = en1; ec2 = en2; ec3 = en3;
    hc0 = hn0; hc1 = hn1; hc2 = hn2; hc3 = hn3;
    sn0 = sm0; sn1 = sm1; sn2 = sm2; sn3 = sm3;
  }
#pragma unroll
  for (int j = 0; j < 4; ++j) {
    *(ushort4*)&zin[(size_t)(n0 + j) * HID + c4] =
        make_ushort4(f2bf(A[j][0]), f2bf(A[j][1]), f2bf(A[j][2]), f2bf(A[j][3]));
  }
}

// Fused layer MLP: one 224x256 row-tile per block, both GEMM stages fused,
// 3 barriers per block total. A-tile staged to LDS once; z1 overwrites it.
// (round-7 note: device-wide spin-barrier BN fusion REVERTED — harness
// poison-fills break co-residency (31ms spin) and the bar cacheline atomics
// serialize across 8 XCDs (218us even when "working"). The kernel boundary
// is the cheap barrier; k_bn_apply stays a separate kernel.)
__global__ __launch_bounds__(512, 1) void k_mlp(const ushort_t* __restrict__ A,
    const ushort_t* __restrict__ Wt1, const float* __restrict__ b1,
    const ushort_t* __restrict__ Wt2, const float* __restrict__ b2,
    ushort_t* __restrict__ out, float* __restrict__ stats, int M)
{
  __shared__ alignas(16) ushort_t T[BMT][264];  // A-tile, then z1 (118 KB)
  int tid = threadIdx.x;
  int wave = tid >> 6, lane = tid & 63;
  int m = lane & 15, quad = lane >> 4;
  int col0 = wave * 32;
  int row0 = blockIdx.x * BMT;

  // ---- stage A-tile -> LDS (coalesced b128; rows >= M clamp to M-1) ----
#pragma unroll
  for (int i = 0; i < 14; ++i) {
    int flat = i * 512 + tid;
    int row = flat >> 5, kc = flat & 31;
    int gr = row0 + row; if (gr > M - 1) gr = M - 1;
    u16x8 v = *(const u16x8*)(A + (size_t)gr * HID + kc * 8);
    *(u16x8*)&T[row][kc * 8] = v;
  }
  bf16x8 w1f[2][8];
#pragma unroll
  for (int nt = 0; nt < 2; ++nt)
#pragma unroll
    for (int kt = 0; kt < 8; ++kt)
      w1f[nt][kt] = *(const bf16x8*)(
          Wt1 + (size_t)(col0 + nt * 16 + m) * HID + kt * 32 + quad * 8);
  float bv1[2] = {b1[col0 + m], b1[col0 + 16 + m]};
  float bv2[2] = {b2[col0 + m], b2[col0 + 16 + m]};
  __syncthreads();

  // ---- stage 1: z1 = relu(A@W1+b1), acc[14][2] over 14 m-tiles ----
  f32x4 acc[14][2];
#pragma unroll
  for (int mt = 0; mt < 14; ++mt) {
    acc[mt][0] = (f32x4){0.f, 0.f, 0.f, 0.f};
    acc[mt][1] = (f32x4){0.f, 0.f, 0.f, 0.f};
    bf16x8 af[8];
#pragma unroll
    for (int kt = 0; kt < 8; ++kt)
      af[kt] = *(const bf16x8*)&T[mt * 16 + m][kt * 32 + quad * 8];
#pragma unroll
    for (int kt = 0; kt < 8; ++kt) {
      acc[mt][0] = __builtin_amdgcn_mfma_f32_16x16x32_bf16(af[kt], w1f[0][kt], acc[mt][0], 0, 0, 0);
      acc[mt][1] = __builtin_amdgcn_mfma_f32_16x16x32_bf16(af[kt], w1f[1][kt], acc[mt][1], 0, 0, 0);
    }
  }
  __syncthreads();  // all waves done reading A-LDS

  // ---- z1 overwrites A-LDS ----
#pragma unroll
  for (int mt = 0; mt < 14; ++mt)
#pragma unroll
    for (int nt = 0; nt < 2; ++nt)
#pragma unroll
      for (int reg = 0; reg < 4; ++reg)
        T[mt * 16 + quad * 4 + reg][col0 + nt * 16 + m] =
            f2bf(fmaxf(acc[mt][nt][reg] + bv1[nt], 0.f));
  bf16x8 w2f[2][8];
#pragma unroll
  for (int nt = 0; nt < 2; ++nt)
#pragma unroll
    for (int kt = 0; kt < 8; ++kt)
      w2f[nt][kt] = *(const bf16x8*)(
          Wt2 + (size_t)(col0 + nt * 16 + m) * HID + kt * 32 + quad * 8);
  __syncthreads();

  // ---- stage 2: z2 = z1@W2+b2 (reuse acc) ----
#pragma unroll
  for (int mt = 0; mt < 14; ++mt) {
    acc[mt][0] = (f32x4){0.f, 0.f, 0.f, 0.f};
    acc[mt][1] = (f32x4){0.f, 0.f, 0.f, 0.f};
    bf16x8 af[8];
#pragma unroll
    for (int kt = 0; kt < 8; ++kt)
      af[kt] = *(const bf16x8*)&T[mt * 16 + m][kt * 32 + quad * 8];
#pragma unroll
    for (int kt = 0; kt < 8; ++kt) {
      acc[mt][0] = __builtin_amdgcn_mfma_f32_16x16x32_bf16(af[kt], w2f[0][kt], acc[mt][0], 0, 0, 0);
      acc[mt][1] = __builtin_amdgcn_mfma_f32_16x16x32_bf16(af[kt], w2f[1][kt], acc[mt][1], 0, 0, 0);
    }
  }

  // ---- store + fused column stats (valid m-tiles only; M % 16 == 0) ----
  float csum[2] = {0.f, 0.f}, csq[2] = {0.f, 0.f};
#pragma unroll
  for (int mt = 0; mt < 14; ++mt) {
    if (row0 + mt * 16 < M) {
#pragma unroll
      for (int nt = 0; nt < 2; ++nt) {
#pragma unroll
        for (int reg = 0; reg < 4; ++reg) {
          float o = acc[mt][nt][reg] + bv2[nt];
          out[(size_t)(row0 + mt * 16 + quad * 4 + reg) * HID + col0 + nt * 16 + m] = f2bf(o);
          csum[nt] += o; csq[nt] = fmaf(o, o, csq[nt]);
        }
      }
    }
  }
#pragma unroll
  for (int nt = 0; nt < 2; ++nt) {
    float s = csum[nt], q = csq[nt];
    s += __shfl_xor(s, 16); s += __shfl_xor(s, 32);
    q += __shfl_xor(q, 16); q += __shfl_xor(q, 32);
    if (quad == 0) {
      unsafeAtomicAdd(&stats[col0 + nt * 16 + m], s);
      unsafeAtomicAdd(&stats[HID + col0 + nt * 16 + m], q);
    }
  }
}

// h(bf16) = relu(z*scale + shift) + h ; 8 elems (16B) per thread (G13)
__global__ __launch_bounds__(256) void k_bn_apply(const ushort_t* __restrict__ z,
    const float* __restrict__ stats, const float* __restrict__ g,
    const float* __restrict__ b, ushort_t* __restrict__ h, int total8)
{
  int idx = blockIdx.x * 256 + threadIdx.x;
  if (idx >= total8) return;
  int col = (idx & 31) * 8;
  const float inv_n = 1.f / (float)N_NODES;
  float sc[8], sh[8];
#pragma unroll
  for (int c = 0; c < 8; ++c) {
    float mu = stats[col + c] * inv_n;
    float var = stats[HID + col + c] * inv_n - mu * mu;
    float rs = rsqrtf(var + 1e-5f);
    sc[c] = g[col + c] * rs;
    sh[c] = b[col + c] - mu * sc[c];
  }
  u16x8 zv = *(const u16x8*)(z + (size_t)idx * 8);
  u16x8 hv = *(const u16x8*)(h + (size_t)idx * 8);
  u16x8 o;
#pragma unroll
  for (int c = 0; c < 8; ++c) {
    float v = fmaxf(fmaf(bf2f(zv[c]), sc[c], sh[c]), 0.f) + bf2f(hv[c]);
    o[c] = f2bf(v);
  }
  *(u16x8*)(h + (size_t)idx * 8) = o;
}

__device__ __forceinline__ int lbound(const int* __restrict__ b, int n, int key) {
  int lo = 0, hi = n;
  while (lo < hi) {
    int mid = (lo + hi) >> 1;
    if (b[mid] < key) lo = mid + 1; else hi = mid;
  }
  return lo;
}

// fused last-layer BN + pool: h_new = relu(z2*sc+sh) + h_old computed on
// the fly. gf[g] = [mean | sum | max] as bf16. Row loop unrolled x2 for
// more loads in flight.
__global__ __launch_bounds__(256) void k_pool_bn(const ushort_t* __restrict__ z,
    const float* __restrict__ stats, const float* __restrict__ g_,
    const float* __restrict__ b_, const ushort_t* __restrict__ h,
    const int* __restrict__ batch, ushort_t* __restrict__ gf)
{
  int g = blockIdx.x, j = threadIdx.x;
  const float inv_n = 1.f / (float)N_NODES;
  float mu = stats[j] * inv_n;
  float var = stats[HID + j] * inv_n - mu * mu;
  float rs = rsqrtf(var + 1e-5f);
  float sc = g_[j] * rs;
  float sh = b_[j] - mu * sc;
  int lo = lbound(batch, N_NODES, g);
  int hi = lbound(batch, N_NODES, g + 1);
  float s = 0.f, mx = 0.f;  // h >= 0 by construction
  int i = lo;
  for (; i + 1 < hi; i += 2) {
    float zv0 = bf2f(z[(size_t)i * HID + j]);
    float hv0 = bf2f(h[(size_t)i * HID + j]);
    float zv1 = bf2f(z[(size_t)(i + 1) * HID + j]);
    float hv1 = bf2f(h[(size_t)(i + 1) * HID + j]);
    float v0 = fmaxf(fmaf(zv0, sc, sh), 0.f) + hv0;
    float v1 = fmaxf(fmaf(zv1, sc, sh), 0.f) + hv1;
    s += v0 + v1;
    mx = fmaxf(mx, fmaxf(v0, v1));
  }
  if (i < hi) {
    float zv = bf2f(z[(size_t)i * HID + j]);
    float hv = bf2f(h[(size_t)i * HID + j]);
    float v = fmaxf(fmaf(zv, sc, sh), 0.f) + hv;
    s += v; mx = fmaxf(mx, v);
  }
  float cntv = fmaxf((float)(hi - lo), 1.f);
  size_t base = (size_t)g * 768;
  gf[base + j] = f2bf(s / cntv);
  gf[base + 256 + j] = f2bf(s);
  gf[base + 512 + j] = f2bf(mx);
}

// small B-in-registers MFMA GEMM for the head: out[M,N] = A[M,K] @ Bt^T + bias
template<int KT, int DO_RELU>
__global__ __launch_bounds__(256, 1) void k_head_gemm(const ushort_t* __restrict__ A,
    const ushort_t* __restrict__ Bt, const float* __restrict__ bias,
    ushort_t* __restrict__ out, int M, int N)
{
  const int K = KT * 32;
  int tid = threadIdx.x;
  int wave = tid >> 6, lane = tid & 63;
  int m = lane & 15, quad = lane >> 4;
  int col = (blockIdx.y * 4 + wave) * 16 + m;
  bf16x8 bfrag[KT];
#pragma unroll
  for (int kt = 0; kt < KT; ++kt)
    bfrag[kt] = *(const bf16x8*)(Bt + (size_t)col * K + kt * 32 + quad * 8);
  float bv = bias[col];
  int ntiles = M >> 4;
  for (int t = blockIdx.x; t < ntiles; t += gridDim.x) {
    const ushort_t* Ap = A + (size_t)(t * 16 + m) * K + quad * 8;
    bf16x8 af[KT];
#pragma unroll
    for (int kt = 0; kt < KT; ++kt) af[kt] = *(const bf16x8*)(Ap + kt * 32);
    f32x4 acc = (f32x4){0.f, 0.f, 0.f, 0.f};
#pragma unroll
    for (int kt = 0; kt < KT; ++kt)
      acc = __builtin_amdgcn_mfma_f32_16x16x32_bf16(af[kt], bfrag[kt], acc, 0, 0, 0);
    int rb = t * 16 + quad * 4;
#pragma unroll
    for (int reg = 0; reg < 4; ++reg) {
      float o = acc[reg] + bv;
      if (DO_RELU) o = fmaxf(o, 0.f);
      out[(size_t)(rb + reg) * N + col] = f2bf(o);
    }
  }
}

// out[g] = dot(g2[g], W3) + b3; one wave per graph
__global__ __launch_bounds__(256) void k_head_out(const ushort_t* __restrict__ g2,
    const float* __restrict__ W3, const float* __restrict__ b3,
    float* __restrict__ out)
{
  int wave = threadIdx.x >> 6, lane = threadIdx.x & 63;
  int g = blockIdx.x * 4 + wave;
  ushort2 v = *(const ushort2*)&g2[(size_t)g * 128 + lane * 2];
  float p = bf2f(v.x) * W3[lane * 2] + bf2f(v.y) * W3[lane * 2 + 1];
#pragma unroll
  for (int off = 32; off > 0; off >>= 1) p += __shfl_down(p, off);
  if (lane == 0) out[g] = p + b3[0];
}

extern "C" void kernel_launch(void* const* d_in, const int* in_sizes, int n_in,
                              void* d_out, int out_size, void* d_ws, size_t ws_size,
                              hipStream_t stream)
{
  const float* x     = (const float*)d_in[0];
  const int*   ei    = (const int*)d_in[1];
  const float* ea    = (const float*)d_in[2];
  const int*   batch = (const int*)d_in[3];
  const float* encW  = (const float*)d_in[4];
  const float* encB  = (const float*)d_in[5];
  const float* edgeW = (const float*)d_in[6];
  const float* edgeB = (const float*)d_in[7];
  const float* W1    = (const float*)d_in[8];
  const float* b1    = (const float*)d_in[9];
  const float* W2    = (const float*)d_in[10];
  const float* b2    = (const float*)d_in[11];
  const float* bng   = (const float*)d_in[12];
  const float* bnb   = (const float*)d_in[13];
  const float* hW1   = (const float*)d_in[14];
  const float* hb1   = (const float*)d_in[15];
  const float* hW2   = (const float*)d_in[16];
  const float* hb2   = (const float*)d_in[17];
  const float* hW3   = (const float*)d_in[18];
  const float* hb3   = (const float*)d_in[19];
  float* out = (float*)d_out;

  const size_t NH = (size_t)N_NODES * HID;
  char* base = (char*)d_ws;
  auto alloc = [&](size_t bytes) -> char* {
    char* p = base; base += (bytes + 63) & ~(size_t)63; return p;
  };
  float*    stats = (float*)alloc(512 * 4);
  int*      offs  = (int*)alloc(50001 * 4);
  int*      pstart= (int*)alloc(50001 * 4);
  int*      btot  = (int*)alloc(64 * 4);
  int*      esrc  = (int*)alloc((size_t)PAD_SLOTS * 4);
  ushort_t* eab   = (ushort_t*)alloc((size_t)PAD_SLOTS * 8 * 2);
  ushort_t* Wt1   = (ushort_t*)alloc((size_t)NLAYERS * HID * HID * 2);
  ushort_t* Wt2   = (ushort_t*)alloc((size_t)NLAYERS * HID * HID * 2);
  ushort_t* hW1t  = (ushort_t*)alloc((size_t)768 * 256 * 2);
  ushort_t* hW2t  = (ushort_t*)alloc((size_t)256 * 128 * 2);
  ushort_t* gf    = (ushort_t*)alloc((size_t)G_GRAPHS * 768 * 2);
  ushort_t* g1    = (ushort_t*)alloc((size_t)G_GRAPHS * 256 * 2);
  ushort_t* g2    = (ushort_t*)alloc((size_t)G_GRAPHS * 128 * 2);
  ushort_t* zin   = (ushort_t*)alloc(NH * 2);  // gather out / z2
  ushort_t* h     = (ushort_t*)alloc(NH * 2);
  // total ~88 MB

  const int* src = ei;
  const int* dst = ei + N_EDGES;

  // setup: padded CSR build + weight prep (once per call)
  hipMemsetAsync(offs, 0, 50001 * sizeof(int), stream);
  // esrc and eab are adjacent allocations: one combined clear
  hipMemsetAsync(esrc, 0, (size_t)((char*)(eab + (size_t)PAD_SLOTS * 8) - (char*)esrc), stream);
  k_hist<<<(N_EDGES + 255) / 256, 256, 0, stream>>>(dst, offs, N_EDGES);
  const int NSB = (N_NODES + 1023) / 1024;  // 49
  k_scanA<<<NSB, 1024, 0, stream>>>(offs, btot, N_NODES);
  k_scanC<<<NSB, 1024, 0, stream>>>(offs, pstart, btot, N_NODES);
  k_fill<<<(N_EDGES + 255) / 256, 256, 0, stream>>>(src, dst, offs, esrc, eab, ea, N_EDGES);
  k_prep<<<dim3(16, 2 * NLAYERS), 256, 0, stream>>>(W1, W2, Wt1, Wt2);
  k_prept<<<(768 * 256 + 255) / 256, 256, 0, stream>>>(hW1, hW1t, 768, 256);
  k_prept<<<(256 * 128 + 255) / 256, 256, 0, stream>>>(hW2, hW2t, 256, 128);

  k_encoder<<<(N_NODES + 7) / 8, 256, 0, stream>>>(x, encW, encB, h, N_NODES);

  const int NB_MLP = (N_NODES + BMT - 1) / BMT;  // 224 blocks, 1 tile each

  for (int l = 0; l < NLAYERS; ++l) {
    k_gather<<<(N_NODES + 15) / 16, 256, 0, stream>>>(
        h, pstart, esrc, eab, edgeW + (size_t)l * 5 * HID, edgeB + (size_t)l * HID,
        zin, stats, N_NODES);
    k_mlp<<<NB_MLP, 512, 0, stream>>>(
        zin, Wt1 + (size_t)l * HID * HID, b1 + (size_t)l * HID,
        Wt2 + (size_t)l * HID * HID, b2 + (size_t)l * HID, zin, stats, N_NODES);
    if (l < NLAYERS - 1) {
      k_bn_apply<<<(N_NODES * HID / 8 + 255) / 256, 256, 0, stream>>>(
          zin, stats, bng + (size_t)l * HID, bnb + (size_t)l * HID, h,
          N_NODES * HID / 8);
    }
  }

  // last layer: BN fused into pool (h only read, never re-written)
  k_pool_bn<<<G_GRAPHS, 256, 0, stream>>>(
      zin, stats, bng + (size_t)(NLAYERS - 1) * HID,
      bnb + (size_t)(NLAYERS - 1) * HID, h, batch, gf);
  k_head_gemm<24, 1><<<dim3(16, 4), 256, 0, stream>>>(gf, hW1t, hb1, g1, G_GRAPHS, 256);
  k_head_gemm<8, 1><<<dim3(16, 2), 256, 0, stream>>>(g1, hW2t, hb2, g2, G_GRAPHS, 128);
  k_head_out<<<G_GRAPHS / 4, 256, 0, stream>>>(g2, hW3, hb3, out);
}